// Round 2
// baseline (114.288 us; speedup 1.0000x reference)
//
#include <hip/hip_runtime.h>

// SemiSparseCRFLoss on MI355X — R6: vertical row-pair per thread.
// R5 post-mortem: 111.2us total, ~97us harness reset, map ~11us. R5's 2x
// row-read amplification (each row loaded as cur AND as nxt by adjacent
// waves) and two serialized guarded segments were the remaining cost.
// R6: each thread owns rows (h0, h0+1) of ONE batch: loads 3 rows (24
// float4) for 2 segments (12/seg vs 16/seg), middle row + its right-halo
// shuffle reused in registers. r2 loads issued before pair-0 compute so
// HBM latency hides under ~130 VALU ops. Block-per-batch layout: skipped
// batches (image_class==0) retire entire blocks immediately.

#define BATCH 16
#define HGT 512
#define WID 512
#define HW (HGT * WID)
#define NBLOCK 1024          // 64 blocks/batch x 16 batches
// block: 4 waves; wave = one row-pair (strip). strips/batch = 256.

#define LOAD8(dst, p) do {                                              \
    float4 _a = *(const float4*)(p);                                    \
    float4 _b = *(const float4*)((p) + 4);                              \
    (dst)[0] = _a.x; (dst)[1] = _a.y; (dst)[2] = _a.z; (dst)[3] = _a.w; \
    (dst)[4] = _b.x; (dst)[5] = _b.y; (dst)[6] = _b.z; (dst)[7] = _b.w; \
} while (0)

__device__ __forceinline__ float pair_loss(
        const float (&cur)[4][8], const float (&nxt)[4][8],
        const float (&cR)[4], const float (&nR)[4], const float (&nL)[4],
        const bool hn, const bool left, const bool right) {
    const float inv2s2 = 22.2222222f;    // 1/(2*0.15^2)
    const float wxy1 = 0.60653066f;      // exp(-1/2): shifts (0,1),(1,0)
    const float wxy2 = 0.36787944f;      // exp(-1):   shifts (1,1),(1,-1)

    float d2r[8], d2d[8], d2dr[8], d2dl[8];
    #pragma unroll
    for (int j = 0; j < 8; j++) { d2r[j] = 0.f; d2d[j] = 0.f; d2dr[j] = 0.f; d2dl[j] = 0.f; }

    #pragma unroll
    for (int c = 0; c < 3; c++) {
        #pragma unroll
        for (int j = 0; j < 8; j++) {
            const float curj = cur[c][j];
            const float cr  = (j < 7) ? cur[c][j + 1] : cR[c];   // (h, w+1)
            const float nd  = nxt[c][j];                          // (h+1, w)
            const float ndr = (j < 7) ? nxt[c][j + 1] : nR[c];   // (h+1, w+1)
            const float ndl = (j > 0) ? nxt[c][j - 1] : nL[c];   // (h+1, w-1)
            float dr  = curj - cr;   d2r[j]  += dr  * dr;
            float dd  = curj - nd;   d2d[j]  += dd  * dd;
            float ddr = curj - ndr;  d2dr[j] += ddr * ddr;
            float ddl = curj - ndl;  d2dl[j] += ddl * ddl;
        }
    }

    float s = 0.f;
    #pragma unroll
    for (int j = 0; j < 8; j++) {
        const float yj  = cur[3][j];
        const float yr  = (j < 7) ? cur[3][j + 1] : cR[3];
        const float yd  = nxt[3][j];
        const float ydr = (j < 7) ? nxt[3][j + 1] : nR[3];
        const float ydl = (j > 0) ? nxt[3][j - 1] : nL[3];
        if (j < 7 || right) {                  // shift (0,1)
            float dy = yj - yr;
            float m = __expf(-d2r[j] * inv2s2) * wxy1 - 0.01f;
            s += m * dy * dy;
        }
        if (hn) {
            {                                   // shift (1,0)
                float dy = yj - yd;
                float m = __expf(-d2d[j] * inv2s2) * wxy1 - 0.01f;
                s += m * dy * dy;
            }
            if (j < 7 || right) {               // shift (1,1)
                float dy = yj - ydr;
                float m = __expf(-d2dr[j] * inv2s2) * wxy2 - 0.01f;
                s += m * dy * dy;
            }
            if (j > 0 || left) {                // shift (1,-1)
                float dy = yj - ydl;
                float m = __expf(-d2dl[j] * inv2s2) * wxy2 - 0.01f;
                s += m * dy * dy;
            }
        }
    }
    return s;
}

__global__ __launch_bounds__(256) void crf_map(
        const float* __restrict__ y_pr,
        const float* __restrict__ image,
        const int* __restrict__ image_class,
        double* __restrict__ partial) {
    const int lane = threadIdx.x & 63;           // column segment (8 px)
    const int wv = threadIdx.x >> 6;             // wave in block
    const int b = blockIdx.x >> 6;               // batch, wave-uniform
    const int strip = ((blockIdx.x & 63) << 2) | wv;  // 0..255 row-pair
    const int h0 = strip << 1;                   // rows h0, h0+1 (+halo h0+2)
    const bool has2 = (strip < 255);             // row h0+2 exists
    const bool left = (lane > 0);
    const bool right = (lane < 63);

    double local = 0.0;
    if (image_class[b] != 0) {
        const float* __restrict__ yb = y_pr + (size_t)b * 2 * HW + HW;
        const float* __restrict__ ib = image + (size_t)b * 3 * HW;
        const int off = h0 * WID + lane * 8;
        const float* base[4] = { ib + off, ib + HW + off, ib + 2 * HW + off, yb + off };

        // ---- rows h0, h0+1: 16 independent float4 loads upfront.
        float r0[4][8], r1[4][8], r2[4][8];
        #pragma unroll
        for (int a = 0; a < 4; a++) {
            LOAD8(r0[a], base[a]);
            LOAD8(r1[a], base[a] + WID);
        }
        // ---- row h0+2: issue before pair-0 compute (latency hidden).
        if (has2) {
            #pragma unroll
            for (int a = 0; a < 4; a++) LOAD8(r2[a], base[a] + 2 * WID);
        } else {
            #pragma unroll
            for (int a = 0; a < 4; a++)
                #pragma unroll
                for (int k = 0; k < 8; k++) r2[a][k] = 0.f;
        }

        // ---- pair-0 halos from neighbor lanes (no global edge loads).
        float cR0[4], nR0[4], nL0[4];
        #pragma unroll
        for (int a = 0; a < 4; a++) {
            cR0[a] = __shfl_down(r0[a][0], 1);   // (h0,   w0+8)
            nR0[a] = __shfl_down(r1[a][0], 1);   // (h0+1, w0+8)
            nL0[a] = __shfl_up(r1[a][7], 1);     // (h0+1, w0-1)
        }

        float s0 = pair_loss(r0, r1, cR0, nR0, nL0, true, left, right);

        // ---- pair-1 halos; cR of row h0+1 == nR0 (register reuse).
        float nR1[4], nL1[4];
        #pragma unroll
        for (int a = 0; a < 4; a++) {
            nR1[a] = __shfl_down(r2[a][0], 1);   // (h0+2, w0+8)
            nL1[a] = __shfl_up(r2[a][7], 1);     // (h0+2, w0-1)
        }

        float s1 = pair_loss(r1, r2, nR0, nR1, nL1, has2, left, right);

        local = (double)s0 + (double)s1;
    }

    // wave64 reduction
    for (int off = 32; off > 0; off >>= 1)
        local += __shfl_down(local, off);

    __shared__ double sdata[4];
    if ((threadIdx.x & 63) == 0) sdata[wv] = local;
    __syncthreads();
    if (threadIdx.x == 0)
        partial[blockIdx.x] = sdata[0] + sdata[1] + sdata[2] + sdata[3];
}

__global__ __launch_bounds__(256) void crf_reduce(
        const double* __restrict__ partial, float* __restrict__ out) {
    double s = 0.0;
    for (int i = threadIdx.x; i < NBLOCK; i += 256)
        s += partial[i];
    for (int off = 32; off > 0; off >>= 1)
        s += __shfl_down(s, off);
    __shared__ double sdata[4];
    const int lane = threadIdx.x & 63;
    const int wv = threadIdx.x >> 6;
    if (lane == 0) sdata[wv] = s;
    __syncthreads();
    if (threadIdx.x == 0) {
        double t = sdata[0] + sdata[1] + sdata[2] + sdata[3];
        out[0] = (float)(t * (1.0 / ((double)HW * BATCH * 4)));
    }
}

extern "C" void kernel_launch(void* const* d_in, const int* in_sizes, int n_in,
                              void* d_out, int out_size, void* d_ws, size_t ws_size,
                              hipStream_t stream) {
    const float* y_pr = (const float*)d_in[0];
    // d_in[1] (y_gt) unused by the reference
    const float* image = (const float*)d_in[2];
    const int* image_class = (const int*)d_in[3];
    float* out = (float*)d_out;
    double* partial = (double*)d_ws;   // NBLOCK doubles = 8 KB

    crf_map<<<NBLOCK, 256, 0, stream>>>(y_pr, image, image_class, partial);
    crf_reduce<<<1, 256, 0, stream>>>(partial, out);
}

// Round 3
// 113.181 us; speedup vs baseline: 1.0098x; 1.0098x over previous
//
#include <hip/hip_runtime.h>

// SemiSparseCRFLoss on MI355X — R7: 1 segment/thread, 2048 blocks, backfill.
// R6 post-mortem: row-pair (3 rows live) blew VGPR past 128 -> 2 waves/SIMD,
// regressed to 114.3 despite fewer loads. Occupancy > load amortization here.
// R7 theory: R5's (b, b+8) pairing makes both-active blocks run 2 serial
// seg chains while both-inactive blocks idle, and the 1024-block grid is
// ~exactly one residency round -> no backfill, makespan ~= 2x seg_time.
// Fix: 2048 blocks, 128/batch, one guarded segment per thread. Inactive
// batches retire instantly; HW backfills freed slots with active blocks.
// seg_loss identical to verified R5 (shuffle halo, absmax 0.0).

#define BATCH 16
#define HGT 512
#define WID 512
#define HW (HGT * WID)
#define SEG 8
#define SEGS_PER_ROW (WID / SEG)            // 64 = one wave per row
#define SEGS_PER_BATCH (HGT * SEGS_PER_ROW) // 32768 = 2^15
#define NBLOCK 2048                          // 128 blocks per batch

__device__ __forceinline__ float seg_loss(
        const float* __restrict__ yb,   // y_pr batch b, channel 1
        const float* __restrict__ ib,   // image batch b
        int seg) {
    const float inv2s2 = 22.2222222f;    // 1/(2*0.15^2)
    const float wxy1 = 0.60653066f;      // exp(-1/2): shifts (0,1),(1,0)
    const float wxy2 = 0.36787944f;      // exp(-1):   shifts (1,1),(1,-1)

    const int h = seg >> 6;
    const int lane = seg & 63;           // == lane id within the wave
    const int w0 = lane * SEG;
    const int hw = h * WID + w0;
    const bool hn = (h + 1 < HGT);       // wave-uniform
    const bool left = (lane > 0);
    const bool right = (lane < 63);

    // ---- Load phase: all 16 float4 issued before any dependent compute.
    // Arrays a=0..2: image channels; a=3: y_pr ch1.
    float c_[4][8];   // row h,   cols w0..w0+7
    float n_[4][8];   // row h+1, cols w0..w0+7
    #pragma unroll
    for (int a = 0; a < 4; a++) {
        const float* __restrict__ p = (a < 3) ? (ib + a * HW + hw) : (yb + hw);
        float4 a0 = *(const float4*)(p);
        float4 a1 = *(const float4*)(p + 4);
        c_[a][0] = a0.x; c_[a][1] = a0.y; c_[a][2] = a0.z; c_[a][3] = a0.w;
        c_[a][4] = a1.x; c_[a][5] = a1.y; c_[a][6] = a1.z; c_[a][7] = a1.w;
        if (hn) {
            float4 b0 = *(const float4*)(p + WID);
            float4 b1 = *(const float4*)(p + WID + 4);
            n_[a][0] = b0.x; n_[a][1] = b0.y; n_[a][2] = b0.z; n_[a][3] = b0.w;
            n_[a][4] = b1.x; n_[a][5] = b1.y; n_[a][6] = b1.z; n_[a][7] = b1.w;
        } else {
            #pragma unroll
            for (int k = 0; k < 8; k++) n_[a][k] = 0.f;
        }
    }

    // ---- Halo phase: neighbor-lane registers instead of global loads.
    float cR[4], nR[4], nL[4];
    #pragma unroll
    for (int a = 0; a < 4; a++) {
        cR[a] = __shfl_down(c_[a][0], 1);   // (h,   w0+8)
        nR[a] = __shfl_down(n_[a][0], 1);   // (h+1, w0+8)
        nL[a] = __shfl_up(n_[a][7], 1);     // (h+1, w0-1)
    }

    // ---- d2 accumulation over 3 image channels.
    float d2r[8], d2d[8], d2dr[8], d2dl[8];
    #pragma unroll
    for (int j = 0; j < 8; j++) { d2r[j] = 0.f; d2d[j] = 0.f; d2dr[j] = 0.f; d2dl[j] = 0.f; }

    #pragma unroll
    for (int c = 0; c < 3; c++) {
        #pragma unroll
        for (int j = 0; j < 8; j++) {
            const float curj = c_[c][j];
            const float cr  = (j < 7) ? c_[c][j + 1] : cR[c];   // (h, w+1)
            const float nd  = n_[c][j];                          // (h+1, w)
            const float ndr = (j < 7) ? n_[c][j + 1] : nR[c];   // (h+1, w+1)
            const float ndl = (j > 0) ? n_[c][j - 1] : nL[c];   // (h+1, w-1)
            float dr  = curj - cr;   d2r[j]  += dr  * dr;
            float dd  = curj - nd;   d2d[j]  += dd  * dd;
            float ddr = curj - ndr;  d2dr[j] += ddr * ddr;
            float ddl = curj - ndl;  d2dl[j] += ddl * ddl;
        }
    }

    // ---- Loss accumulation (y = array 3).
    float s = 0.f;
    #pragma unroll
    for (int j = 0; j < 8; j++) {
        const float yj  = c_[3][j];
        const float yr  = (j < 7) ? c_[3][j + 1] : cR[3];
        const float yd  = n_[3][j];
        const float ydr = (j < 7) ? n_[3][j + 1] : nR[3];
        const float ydl = (j > 0) ? n_[3][j - 1] : nL[3];
        if (j < 7 || right) {                  // shift (0,1)
            float dy = yj - yr;
            float m = __expf(-d2r[j] * inv2s2) * wxy1 - 0.01f;
            s += m * dy * dy;
        }
        if (hn) {
            {                                   // shift (1,0)
                float dy = yj - yd;
                float m = __expf(-d2d[j] * inv2s2) * wxy1 - 0.01f;
                s += m * dy * dy;
            }
            if (j < 7 || right) {               // shift (1,1)
                float dy = yj - ydr;
                float m = __expf(-d2dr[j] * inv2s2) * wxy2 - 0.01f;
                s += m * dy * dy;
            }
            if (j > 0 || left) {                // shift (1,-1)
                float dy = yj - ydl;
                float m = __expf(-d2dl[j] * inv2s2) * wxy2 - 0.01f;
                s += m * dy * dy;
            }
        }
    }
    return s;
}

__global__ __launch_bounds__(256) void crf_map(
        const float* __restrict__ y_pr,
        const float* __restrict__ image,
        const int* __restrict__ image_class,
        double* __restrict__ partial) {
    // 128 blocks per batch; one segment per thread.
    // seg & 63 == threadIdx.x & 63, so shuffle-halo lane math holds.
    const int b = blockIdx.x >> 7;                         // wave-uniform
    const int seg = ((blockIdx.x & 127) << 8) | threadIdx.x; // 0..32767

    double local = 0.0;
    if (image_class[b] != 0) {
        const float* yb = y_pr + (size_t)b * 2 * HW + HW;
        const float* ib = image + (size_t)b * 3 * HW;
        local = (double)seg_loss(yb, ib, seg);
    }

    // wave64 reduction
    for (int off = 32; off > 0; off >>= 1)
        local += __shfl_down(local, off);

    __shared__ double sdata[4];
    const int lane = threadIdx.x & 63;
    const int wv = threadIdx.x >> 6;
    if (lane == 0) sdata[wv] = local;
    __syncthreads();
    if (threadIdx.x == 0)
        partial[blockIdx.x] = sdata[0] + sdata[1] + sdata[2] + sdata[3];
}

__global__ __launch_bounds__(256) void crf_reduce(
        const double* __restrict__ partial, float* __restrict__ out) {
    double s = 0.0;
    for (int i = threadIdx.x; i < NBLOCK; i += 256)
        s += partial[i];
    for (int off = 32; off > 0; off >>= 1)
        s += __shfl_down(s, off);
    __shared__ double sdata[4];
    const int lane = threadIdx.x & 63;
    const int wv = threadIdx.x >> 6;
    if (lane == 0) sdata[wv] = s;
    __syncthreads();
    if (threadIdx.x == 0) {
        double t = sdata[0] + sdata[1] + sdata[2] + sdata[3];
        out[0] = (float)(t * (1.0 / ((double)HW * BATCH * 4)));
    }
}

extern "C" void kernel_launch(void* const* d_in, const int* in_sizes, int n_in,
                              void* d_out, int out_size, void* d_ws, size_t ws_size,
                              hipStream_t stream) {
    const float* y_pr = (const float*)d_in[0];
    // d_in[1] (y_gt) unused by the reference
    const float* image = (const float*)d_in[2];
    const int* image_class = (const int*)d_in[3];
    float* out = (float*)d_out;
    double* partial = (double*)d_ws;   // NBLOCK doubles = 16 KB

    crf_map<<<NBLOCK, 256, 0, stream>>>(y_pr, image, image_class, partial);
    crf_reduce<<<1, 256, 0, stream>>>(partial, out);
}